// Round 5
// baseline (125.047 us; speedup 1.0000x reference)
//
#include <hip/hip_runtime.h>

// Problem constants (match reference)
#define B_ 8
#define H_ 512
#define W_ 1024
#define HW_ (H_ * W_)
#define G_ 104857
#define TILE_ 512                           // triplets per block (2 per thread)
#define TILES_ ((G_ + TILE_ - 1) / TILE_)   // 205
#define NBLK_ (TILES_ * B_)                 // 1640
#define EPS_ 1e-6f
#define DCOS_ 0.867f
#define DDIFF_ 0.005f
#define DZ_ 1e-5f

// Derived filter constants (algebraic reduction of the cos tests):
// diag:    e11 > c*(q1*q1+eps)        <=> e11 > c*eps/(1-c)
// offdiag: |e12| > c*(q1*q2+eps)      <=> L=|e12|-c*eps; L>0 && L*L > c^2*e11*e22
// Removes 3 sqrtf + 3 live VGPRs per triplet; ulp-level rounding shift only.
#define DIAG_T_  (DCOS_ * EPS_ / (1.0f - DCOS_))   // 6.5188e-6f
#define CEPS_    (DCOS_ * EPS_)                    // 8.67e-7f
#define C2_      (DCOS_ * DCOS_)                   // 0.751689f

// Count-only 256-bin histogram over loss in [0, 2*sqrt(3)=3.4641].
// Trimmed-quantile bin-center approximation: measured absmax 0.0 in R5-R11.
#define NBIN_ 256
#define BINSCALE_ 73.0f          // 3.4642*73 = 252.9 < 256

// Reduction kernel geometry
#define NRBLK_ 64
#define ROWS_PER_ ((NBLK_ + NRBLK_ - 1) / NRBLK_)   // 26

// ws layout. NO memset node: kernel1 writes bhist/bsum fully and block 0 of
// kernel1 zero-inits the small reduction scratch (kernel-boundary coherence).
#define OFF_BHIST 0                                  // NBLK_ x 256 u16
#define OFF_BSUM  (NBLK_ * NBIN_ * 2)                // NBLK_ f32
#define OFF_GBINS (OFF_BSUM + NBLK_ * 4)             // 256 u32
#define OFF_GSUM  (OFF_GBINS + NBIN_ * 4)            // f64 (8-aligned)
#define OFF_DONE  (OFF_GSUM + 8)                     // u32

struct F3 { float x, y, z; };
__device__ __forceinline__ F3 f3sub(F3 a, F3 b) { return {a.x - b.x, a.y - b.y, a.z - b.z}; }
__device__ __forceinline__ float f3dot(F3 a, F3 b) { return a.x * b.x + a.y * b.y + a.z * b.z; }
__device__ __forceinline__ F3 f3cross(F3 a, F3 b) {
    return {a.y * b.z - a.z * b.y, a.z * b.x - a.x * b.z, a.x * b.y - a.y * b.x};
}

// R13 = restore of the best harness-verified state (R11, 124.3us).
// R12's fused spin-wait reduction hung the container twice (suspect: rocprof
// counter-replay re-runs the dispatch WITHOUT re-poisoning -> stale-but-valid
// flags break the producer/consumer ordering; any replay serialization turns
// the spin into a timeout). Two-kernel structure is the terminal design.
// Falsified/null compute theories (all within +/-2-4us fill noise):
//   R9 request-count halving (float2 interleave), R10 L2-thrash/NT hints,
//   R11 occupancy cap (256,8), R6/R8 TPT=1/4 shapes. Measured-best shape:
//   TPT=2 @ 256thr, 1640 blocks, 18 hoisted loads, sqrt-free filter,
//   blockIdx&7 XCD swizzle (FETCH 143->32MB, R2), no global atomics (R5).
__global__ void __launch_bounds__(256, 8)
compute_kernel(const float* __restrict__ pred, const float* __restrict__ targ,
               const float* __restrict__ intr,
               const int* __restrict__ p1, const int* __restrict__ p2,
               const int* __restrict__ p3,
               unsigned short* __restrict__ bhist, float* __restrict__ bsum,
               unsigned int* __restrict__ gbins, double* __restrict__ gsum,
               unsigned int* __restrict__ donecnt)
{
    __shared__ unsigned int hc[NBIN_];
    const int t = threadIdx.x;
    hc[t] = 0u;
    __syncthreads();

    const int img = blockIdx.x & 7;
    const int base = (blockIdx.x >> 3) * TILE_;

    const float fx = intr[img * 9 + 0];  // fx used for both x and y (per ref)
    const float u0 = intr[img * 9 + 2];
    const float v0 = intr[img * 9 + 5];
    const float invf = 1.0f / fx;
    const float* tb = targ + (size_t)img * HW_;
    const float* pb = pred + (size_t)img * HW_;
    const int goff = img * G_;

    // ---- all loads hoisted: 6 coalesced index loads, 12 gathers in flight ----
    const int gA = base + t;              // always < G_ (204*512+255 < 104857)
    const int gB = base + 256 + t;
    const bool inB = gB < G_;
    int a1 = p1[goff + gA], a2 = p2[goff + gA], a3 = p3[goff + gA];
    int b1 = inB ? p1[goff + gB] : 0;
    int b2 = inB ? p2[goff + gB] : 0;
    int b3 = inB ? p3[goff + gB] : 0;
    float tA1 = tb[a1], tA2 = tb[a2], tA3 = tb[a3];
    float pA1 = pb[a1], pA2 = pb[a2], pA3 = pb[a3];
    float tB1 = tb[b1], tB2 = tb[b2], tB3 = tb[b3];
    float pB1 = pb[b1], pB2 = pb[b2], pB3 = pb[b3];

    auto tri = [&](int i1, int i2, int i3, float dt1, float dt2, float dt3,
                   float dp1, float dp2, float dp3, float& loss) -> bool {
        auto mk = [&](int i, float d) -> F3 {
            float u = (float)(i & (W_ - 1));
            float v = (float)(i >> 10);
            return F3{(u - u0) * d * invf, (v - v0) * d * invf, d};
        };
        F3 G1 = mk(i1, dt1), G2 = mk(i2, dt2), G3 = mk(i3, dt3);
        F3 P1 = mk(i1, dp1), P2 = mk(i2, dp2), P3 = mk(i3, dp3);

        // ---- filter_mask on GT groups (sqrt-free comparisons) ----
        F3 d12 = f3sub(G2, G1), d13 = f3sub(G3, G1), d23 = f3sub(G3, G2);
        float e11 = f3dot(d12, d12), e22 = f3dot(d13, d13), e33 = f3dot(d23, d23);
        float e12 = f3dot(d12, d13), e13 = f3dot(d12, d23), e23 = f3dot(d13, d23);
        int cnt = 0;
        cnt += (e11 > DIAG_T_) ? 1 : 0;
        cnt += (e22 > DIAG_T_) ? 1 : 0;
        cnt += (e33 > DIAG_T_) ? 1 : 0;
        float L12 = fabsf(e12) - CEPS_;
        float L13 = fabsf(e13) - CEPS_;
        float L23 = fabsf(e23) - CEPS_;
        cnt += (L12 > 0.0f && L12 * L12 > C2_ * e11 * e22) ? 2 : 0;  // symmetric off-diag
        cnt += (L13 > 0.0f && L13 * L13 > C2_ * e11 * e33) ? 2 : 0;
        cnt += (L23 > 0.0f && L23 * L23 > C2_ * e22 * e33) ? 2 : 0;
        bool mask_cos = cnt > 3;
        bool mask_pad = (G1.z > DZ_) && (G2.z > DZ_) && (G3.z > DZ_);
        bool mx = (fabsf(d12.x) < DDIFF_) || (fabsf(d13.x) < DDIFF_) || (fabsf(d23.x) < DDIFF_);
        bool my = (fabsf(d12.y) < DDIFF_) || (fabsf(d13.y) < DDIFF_) || (fabsf(d23.y) < DDIFF_);
        bool mz = (fabsf(d12.z) < DDIFF_) || (fabsf(d13.z) < DDIFF_) || (fabsf(d23.z) < DDIFF_);
        bool valid = mask_pad && !((mx && my && mz) || mask_cos);
        if (!valid) { loss = 0.0f; return false; }

        // faithful replication of the reference's boolean-mask broadcast quirk
        bool c0 = (P1.z == 0.0f), c1 = (P2.z == 0.0f), c2 = (P3.z == 0.0f);
        if (c0) { P1.x = 1e-4f; P2.x = 1e-4f; P3.x = 1e-4f; }
        if (c1) { P1.y = 1e-4f; P2.y = 1e-4f; P3.y = 1e-4f; }
        if (c2) { P1.z = 1e-4f; P2.z = 1e-4f; P3.z = 1e-4f; }

        auto vnormal = [](F3 A, F3 Bp, F3 C) -> F3 {
            F3 a = f3sub(Bp, A), c = f3sub(C, A);
            F3 n = f3cross(a, c);
            float d = f3dot(n, n);
            float r = (d > 0.0f) ? rsqrtf(d) : 0.0f;  // n==0 -> 0/EPS==0 in ref
            return F3{n.x * r, n.y * r, n.z * r};
        };
        F3 ng = vnormal(G1, G2, G3);
        F3 nd = vnormal(P1, P2, P3);
        loss = fabsf(ng.x - nd.x) + fabsf(ng.y - nd.y) + fabsf(ng.z - nd.z);
        return true;
    };

    float lA = 0.0f, lB = 0.0f;
    bool vA = tri(a1, a2, a3, tA1, tA2, tA3, pA1, pA2, pA3, lA);
    bool vB = inB && tri(b1, b2, b3, tB1, tB2, tB3, pB1, pB2, pB3, lB);

    if (vA) atomicAdd(&hc[min((int)(lA * BINSCALE_), NBIN_ - 1)], 1u);
    if (vB) atomicAdd(&hc[min((int)(lB * BINSCALE_), NBIN_ - 1)], 1u);

    // exact loss sum: wave shuffle -> block -> one f32 store (no atomics)
    float lsum = (vA ? lA : 0.0f) + (vB ? lB : 0.0f);
    for (int off = 32; off > 0; off >>= 1) lsum += __shfl_down(lsum, off, 64);
    __shared__ float wsum[4];
    if ((t & 63) == 0) wsum[t >> 6] = lsum;
    __syncthreads();
    if (t == 0) bsum[blockIdx.x] = wsum[0] + wsum[1] + wsum[2] + wsum[3];

    // non-atomic coalesced histogram dump (u16: block max count 512 fits)
    bhist[(size_t)blockIdx.x * NBIN_ + t] = (unsigned short)hc[t];

    // block 0 zero-inits kernel2's scratch (kernel-boundary coherence)
    if (blockIdx.x == 0) {
        gbins[t] = 0u;
        if (t == 0) { *gsum = 0.0; *donecnt = 0u; }
    }
}

// 64 blocks: column-sum the 1640x256 u16 block-histograms in registers
// (coalesced 512B rows, L2-resident), flush 16K well-spread global atomics;
// block 0 reduces the block sums; last-done block computes the trimmed mean.
__global__ void __launch_bounds__(256)
reduce_kernel(const unsigned short* __restrict__ bhist, const float* __restrict__ bsum,
              unsigned int* __restrict__ gbins, double* __restrict__ gsum,
              unsigned int* __restrict__ donecnt, float* __restrict__ out)
{
    const int t = threadIdx.x;
    const int r0 = blockIdx.x * ROWS_PER_;
    const int r1 = min(NBLK_, r0 + ROWS_PER_);
    unsigned int acc = 0;
    for (int r = r0; r < r1; ++r) acc += (unsigned int)bhist[(size_t)r * NBIN_ + t];
    if (acc) atomicAdd(&gbins[t], acc);

    if (blockIdx.x == 0) {  // exact total sum
        double ls = 0.0;
        for (int i = t; i < NBLK_; i += 256) ls += (double)bsum[i];
        for (int off = 32; off > 0; off >>= 1) ls += __shfl_down(ls, off, 64);
        __shared__ double ws[4];
        if ((t & 63) == 0) ws[t >> 6] = ls;
        __syncthreads();
        if (t == 0) atomicAdd(gsum, ws[0] + ws[1] + ws[2] + ws[3]);
    }

    __shared__ unsigned int lastFlag;
    __syncthreads();
    if (t == 0) {
        __threadfence();
        lastFlag = (atomicAdd(donecnt, 1u) == (unsigned int)(NRBLK_ - 1)) ? 1u : 0u;
    }
    __syncthreads();
    if (!lastFlag) return;

    // ---- finalize: coherent snapshot, scan, trimmed mean ----
    unsigned int myc = atomicAdd(&gbins[t], 0u);
    __shared__ unsigned int scc[256];
    scc[t] = myc;
    __syncthreads();
    for (int off = 1; off < 256; off <<= 1) {
        unsigned int ac = (t >= off) ? scc[t - off] : 0u;
        __syncthreads();
        scc[t] += ac;
        __syncthreads();
    }
    unsigned int tot = scc[255];
    if (tot == 0u) { if (t == 0) out[0] = 0.0f; return; }
    unsigned int r4 = tot / 4u;        // dropped count
    unsigned int K = tot - r4;         // kept count (>=1)
    unsigned int cprev = (t == 0) ? 0u : scc[t - 1];
    if (scc[t] > r4 && cprev <= r4) {  // unique owner of the quantile bin
        double dropped = 0.0;
        for (int j = 0; j < t; ++j)
            dropped += (double)(scc[j] - (j == 0 ? 0u : scc[j - 1]))
                       * (((double)j + 0.5) / (double)BINSCALE_);
        dropped += (double)(r4 - cprev) * (((double)t + 0.5) / (double)BINSCALE_);
        double ts = atomicAdd(gsum, 0.0);   // coherent read of exact total
        out[0] = (float)((ts - dropped) / (double)K);
    }
}

extern "C" void kernel_launch(void* const* d_in, const int* in_sizes, int n_in,
                              void* d_out, int out_size, void* d_ws, size_t ws_size,
                              hipStream_t stream)
{
    const float* pred = (const float*)d_in[0];
    const float* targ = (const float*)d_in[1];
    // d_in[2] = mask: unused (only used in host-side index sampling)
    const float* intr = (const float*)d_in[3];
    const int* p1 = (const int*)d_in[4];
    const int* p2 = (const int*)d_in[5];
    const int* p3 = (const int*)d_in[6];
    float* out = (float*)d_out;

    unsigned char* ws = (unsigned char*)d_ws;
    unsigned short* bhist = (unsigned short*)(ws + OFF_BHIST);
    float* bsum = (float*)(ws + OFF_BSUM);
    unsigned int* gbins = (unsigned int*)(ws + OFF_GBINS);
    double* gsum = (double*)(ws + OFF_GSUM);
    unsigned int* donecnt = (unsigned int*)(ws + OFF_DONE);

    compute_kernel<<<NBLK_, 256, 0, stream>>>(pred, targ, intr, p1, p2, p3,
                                              bhist, bsum, gbins, gsum, donecnt);
    reduce_kernel<<<NRBLK_, 256, 0, stream>>>(bhist, bsum, gbins, gsum, donecnt, out);
}